// Round 11
// baseline (179.551 us; speedup 1.0000x reference)
//
#include <hip/hip_runtime.h>
#include <hip/hip_bf16.h>
#include <math.h>

// HIR rainfall-runoff scan — bracketed time-chunking + exact fixup (R11).
// Skeleton = R8 (fastest validated, 52us pass1). Changes:
//  - warm-up phase 1 (all but last 64 steps) runs dual sms-only chains:
//    gw contributions older than 64 steps decay x(1-RecK)^64 ~ 3e-5
//    (guarded: disabled if RecK < 0.1, wave-uniform branch)
//  - S-clamp lower bound removed (all states provably >= 0 by induction)
//  - W 320 -> 288 (expected bracket gap ~0.77 ~= TOL; misses -> pass2 exact)
//  - exp2 via __builtin_amdgcn_exp2f (single v_exp_f32)
//
// Step math: heaviside -> min/max (exact, continuous at switch points),
// provably-redundant clamps removed, exp(-SQ*S/SMSC)=exp2(c2*S).
// T=1024 -> NC=16 chunks of CH=64; bracket (lo from 0, hi from SMSC;
// monotone map => invariant). Merge if gap <= 0.75, adopt midpoint;
// unmerged chunks recomputed EXACTLY by pass 2 from predecessor end state.
// Q[b,t] (t>=1) = fluxes from carry entering step t; Q[b,0] uses the FINAL
// carry (jnp.roll wraparound) with t=0 inputs (chunk NC-1 / pass2 owns it).

struct P {
    float INSC, COEFF, SMSC, RecK, k1, k2, k3, c2;
};

__device__ __forceinline__ P make_params(const float* pINSC, const float* pCOEFF,
                                         const float* pSQ,   const float* pSMSC,
                                         const float* pSUB,  const float* pCRAK,
                                         const float* pRecK) {
    P p;
    p.INSC  = fminf(fmaxf(pINSC[0]  * 5.0f,   0.5f),   5.0f);
    p.COEFF = fminf(fmaxf(pCOEFF[0] * 400.0f, 50.0f),  400.0f);
    float SQ = fminf(fmaxf(pSQ[0]   * 6.0f,   0.0f),   6.0f);
    p.SMSC  = fminf(fmaxf(pSMSC[0]  * 500.0f, 50.0f),  500.0f);
    float SUB  = fminf(fmaxf(pSUB[0],  0.0f), 1.0f);
    float CRAK = fminf(fmaxf(pCRAK[0], 0.0f), 1.0f);
    p.RecK  = fminf(fmaxf(pRecK[0]  * 0.3f,   0.003f), 0.3f);
    float inv = 1.0f / p.SMSC;
    p.k1 = SUB * inv;
    p.k2 = CRAK * inv;
    p.k3 = 10.0f * inv;
    p.c2 = (-SQ * inv) * 1.44269504088896340736f;
    return p;
}

__device__ __forceinline__ float hexp2(float x) {
    return __builtin_amdgcn_exp2f(x);     // v_exp_f32
}

// Full step with Q. States provably >= 0 -> S = min(sms, SMSC) only.
__device__ __forceinline__ float step(float Prec, float PET, float& sms, float& gw, const P& p) {
    float INT   = fminf(fminf(p.INSC, PET), Prec);
    float INR   = Prec - INT;
    float POT   = PET - INT;
    float S     = fminf(sms, p.SMSC);
    float cap   = p.COEFF * hexp2(p.c2 * S);
    float RMO   = fminf(INR, cap);
    float IRUN  = INR - RMO;
    float SRUN  = (p.k1 * S) * RMO;
    float t2    = RMO - SRUN;
    float REC   = (p.k2 * S) * t2;
    float SMF   = t2 - REC;
    float ETS   = fminf(POT, p.k3 * S);
    float s2    = S + (SMF - ETS);
    float RECnew = REC + fmaxf(s2 - p.SMSC, 0.0f);
    float BAS   = p.RecK * gw;
    float Q     = (SRUN + IRUN) + BAS;
    sms = s2;
    gw  = gw + (RECnew - BAS);
    return Q;
}

// sms-only single-chain update (shared input terms passed in).
__device__ __forceinline__ float supd(float INR, float POT, float s, const P& p) {
    float S     = fminf(s, p.SMSC);
    float cap   = p.COEFF * hexp2(p.c2 * S);
    float RMO   = fminf(INR, cap);
    float SRUN  = (p.k1 * S) * RMO;
    float t2    = RMO - SRUN;
    float REC   = (p.k2 * S) * t2;
    float SMF   = t2 - REC;
    float ETS   = fminf(POT, p.k3 * S);
    return S + (SMF - ETS);
}

// Phase-1 warm-up: dual sms-only (no gw).
__device__ __forceinline__ void dstep_ss(float Prec, float PET,
                                         float& slo, float& shi, const P& p) {
    float INT = fminf(fminf(p.INSC, PET), Prec);
    float INR = Prec - INT;
    float POT = PET - INT;
    shi = supd(INR, POT, shi, p);
    slo = supd(INR, POT, slo, p);
}

// Phase-2 warm-up: hi chain with gw, lo sms-only.
__device__ __forceinline__ void dstep_g(float Prec, float PET,
                                        float& slo, float& shi, float& gw, const P& p) {
    float INT = fminf(fminf(p.INSC, PET), Prec);
    float INR = Prec - INT;
    float POT = PET - INT;
    {   // hi + gw
        float S     = fminf(shi, p.SMSC);
        float cap   = p.COEFF * hexp2(p.c2 * S);
        float RMO   = fminf(INR, cap);
        float SRUN  = (p.k1 * S) * RMO;
        float t2    = RMO - SRUN;
        float REC   = (p.k2 * S) * t2;
        float SMF   = t2 - REC;
        float ETS   = fminf(POT, p.k3 * S);
        float s2    = S + (SMF - ETS);
        float RECnew = REC + fmaxf(s2 - p.SMSC, 0.0f);
        float BAS   = p.RecK * gw;
        gw  = gw + (RECnew - BAS);
        shi = s2;
    }
    slo = supd(INR, POT, slo, p);
}

#define MERGE_TOL 0.75f

template<int T, int NC, int W>
__global__ __launch_bounds__(64, 1)
void hir_pass1(const float* __restrict__ inputs,
               const float* __restrict__ pINSC,  const float* __restrict__ pCOEFF,
               const float* __restrict__ pSQ,    const float* __restrict__ pSMSC,
               const float* __restrict__ pSUB,   const float* __restrict__ pCRAK,
               const float* __restrict__ pRecK,
               float* __restrict__ out, float4* __restrict__ st, int B)
{
    int gid = blockIdx.x * blockDim.x + threadIdx.x;
    int b = gid % B;            // consecutive lanes -> consecutive rows
    int c = gid / B;            // wave-uniform (B % 64 == 0)
    if (c >= NC) return;

    P p = make_params(pINSC, pCOEFF, pSQ, pSMSC, pSUB, pCRAK, pRecK);

    const float4* __restrict__ rp = (const float4*)(inputs + (size_t)b * (2 * T));
    float* __restrict__ orow = out + (size_t)b * T;

    constexpr int CH = T / NC;             // 64 steps
    const int i1 = c * (CH >> 1);          // first main float4 index
    int i0 = i1 - (W >> 1);                // warm-up start
    const bool exact = (i0 <= 0);
    if (i0 < 0) i0 = 0;
    int ip2 = i1 - 32;                     // phase-2 start: last 64 steps
    if (ip2 < i0) ip2 = i0;
    if (p.RecK < 0.1f) ip2 = i0;           // slow gw decay: full-gw warm-up

    float slo = 0.0f, shi = exact ? 0.0f : p.SMSC, gw = 0.0f;

    // ---- Phase 1: [i0, ip2), dual sms-only, R8 batch pipeline ----
    {
        const int nb = (ip2 - i0) >> 2;
        if (nb > 0) {
            float4 A[4], Bq[4], C[4];
            #pragma unroll
            for (int j = 0; j < 4; ++j) A[j] = rp[i0 + j];
            int k1b = (1 < nb) ? 1 : 0;
            #pragma unroll
            for (int j = 0; j < 4; ++j) Bq[j] = rp[i0 + 4 * k1b + j];
            for (int k = 0; k < nb; ++k) {
                int kn = (k + 2 < nb) ? (k + 2) : (nb - 1);
                #pragma unroll
                for (int j = 0; j < 4; ++j) C[j] = rp[i0 + 4 * kn + j];
                #pragma unroll
                for (int j = 0; j < 4; ++j) {
                    dstep_ss(A[j].x, A[j].y, slo, shi, p);
                    dstep_ss(A[j].z, A[j].w, slo, shi, p);
                }
                #pragma unroll
                for (int j = 0; j < 4; ++j) { A[j] = Bq[j]; Bq[j] = C[j]; }
            }
        }
    }

    // ---- Phase 2: [ip2, i1), dual with gw ----
    {
        const int nb = (i1 - ip2) >> 2;
        if (nb > 0) {
            float4 A[4], Bq[4], C[4];
            #pragma unroll
            for (int j = 0; j < 4; ++j) A[j] = rp[ip2 + j];
            int k1b = (1 < nb) ? 1 : 0;
            #pragma unroll
            for (int j = 0; j < 4; ++j) Bq[j] = rp[ip2 + 4 * k1b + j];
            for (int k = 0; k < nb; ++k) {
                int kn = (k + 2 < nb) ? (k + 2) : (nb - 1);
                #pragma unroll
                for (int j = 0; j < 4; ++j) C[j] = rp[ip2 + 4 * kn + j];
                #pragma unroll
                for (int j = 0; j < 4; ++j) {
                    dstep_g(A[j].x, A[j].y, slo, shi, gw, p);
                    dstep_g(A[j].z, A[j].w, slo, shi, gw, p);
                }
                #pragma unroll
                for (int j = 0; j < 4; ++j) { A[j] = Bq[j]; Bq[j] = C[j]; }
            }
        }
    }

    const bool merged = exact || ((shi - slo) <= MERGE_TOL);
    float sms = 0.5f * (slo + shi);        // exact: slo==shi bitwise

    // ---- Main chunk: 32 float4s, R8 pipeline, store Q pairs ----
    {
        constexpr int nmb = (CH / 2) / 4;  // 8 batches
        float4 A[4], Bq[4], C[4];
        #pragma unroll
        for (int j = 0; j < 4; ++j) A[j] = rp[i1 + j];
        #pragma unroll
        for (int j = 0; j < 4; ++j) Bq[j] = rp[i1 + 4 + j];
        for (int k = 0; k < nmb; ++k) {
            int kn = (k + 2 < nmb) ? (k + 2) : (nmb - 1);
            #pragma unroll
            for (int j = 0; j < 4; ++j) C[j] = rp[i1 + 4 * kn + j];
            int ibase = i1 + 4 * k;
            #pragma unroll
            for (int j = 0; j < 4; ++j) {
                float qa = step(A[j].x, A[j].y, sms, gw, p);
                float qb = step(A[j].z, A[j].w, sms, gw, p);
                if (c == 0 && k == 0 && j == 0) {
                    orow[1] = qb;          // t=0 owned by the c=NC-1 path
                } else {
                    ((float2*)orow)[ibase + j] = make_float2(qa, qb);
                }
            }
            #pragma unroll
            for (int j = 0; j < 4; ++j) { A[j] = Bq[j]; Bq[j] = C[j]; }
        }
    }

    st[(size_t)c * B + b] = make_float4(sms, gw, merged ? 1.0f : 0.0f, 0.0f);

    if (c == NC - 1) {
        float4 f0 = rp[0];
        float ss = sms, gg = gw;
        orow[0] = step(f0.x, f0.y, ss, gg, p);
    }
}

template<int T, int NC>
__global__ __launch_bounds__(64, 1)
void hir_pass2(const float* __restrict__ inputs,
               const float* __restrict__ pINSC,  const float* __restrict__ pCOEFF,
               const float* __restrict__ pSQ,    const float* __restrict__ pSMSC,
               const float* __restrict__ pSUB,   const float* __restrict__ pCRAK,
               const float* __restrict__ pRecK,
               float* __restrict__ out, const float4* __restrict__ st, int B)
{
    int b = blockIdx.x * blockDim.x + threadIdx.x;
    if (b >= B) return;

    P p = make_params(pINSC, pCOEFF, pSQ, pSMSC, pSUB, pCRAK, pRecK);
    constexpr int CH = T / NC;

    const float4* __restrict__ rp = (const float4*)(inputs + (size_t)b * (2 * T));
    float* __restrict__ orow = out + (size_t)b * T;

    float4 s0 = st[b];                 // chunk 0: always exact
    float ex_s = s0.x, ex_g = s0.y;

    for (int c = 1; c < NC; ++c) {
        float4 sc = st[(size_t)c * B + b];
        if (sc.z != 0.0f) {
            ex_s = sc.x; ex_g = sc.y;
            continue;
        }
        float sms = ex_s, gw = ex_g;
        const int i1 = c * (CH >> 1);
        const int i2 = (c + 1) * (CH >> 1);
        float4 cur = rp[i1];
        for (int i = i1; i < i2; ++i) {
            int ni = (i + 1 < i2) ? (i + 1) : i;
            float4 nxt = rp[ni];
            float qa = step(cur.x, cur.y, sms, gw, p);
            float qb = step(cur.z, cur.w, sms, gw, p);
            ((float2*)orow)[i] = make_float2(qa, qb);
            cur = nxt;
        }
        ex_s = sms; ex_g = gw;
        if (c == NC - 1) {
            float4 f0 = rp[0];
            float ss = sms, gg = gw;
            orow[0] = step(f0.x, f0.y, ss, gg, p);
        }
    }
}

// Fallback: monolithic sequential (odd shapes / tiny workspace).
template<int T>
__global__ __launch_bounds__(64, 1)
void hir_scan_kernel(const float* __restrict__ inputs,
                     const float* __restrict__ pINSC,  const float* __restrict__ pCOEFF,
                     const float* __restrict__ pSQ,    const float* __restrict__ pSMSC,
                     const float* __restrict__ pSUB,   const float* __restrict__ pCRAK,
                     const float* __restrict__ pRecK,
                     float* __restrict__ out, int B)
{
    int b = blockIdx.x * blockDim.x + threadIdx.x;
    if (b >= B) return;
    P p = make_params(pINSC, pCOEFF, pSQ, pSMSC, pSUB, pCRAK, pRecK);
    const float4* __restrict__ rp = (const float4*)(inputs + (size_t)b * (2 * T));
    float* __restrict__ orow = out + (size_t)b * T;
    float sms = 0.0f, gw = 0.0f;
    float4 cur = rp[0];
    const float P0 = cur.x, E0 = cur.y;
    constexpr int NI = T / 2;
    for (int i = 0; i < NI; ++i) {
        int ni = (i + 1 < NI) ? (i + 1) : i;
        float4 nxt = rp[ni];
        float qa = step(cur.x, cur.y, sms, gw, p);
        float qb = step(cur.z, cur.w, sms, gw, p);
        if (i == 0) { orow[1] = qb; }
        else        { ((float2*)orow)[i] = make_float2(qa, qb); }
        cur = nxt;
    }
    float ss = sms, gg = gw;
    orow[0] = step(P0, E0, ss, gg, p);
}

extern "C" void kernel_launch(void* const* d_in, const int* in_sizes, int n_in,
                              void* d_out, int out_size, void* d_ws, size_t ws_size,
                              hipStream_t stream) {
    (void)n_in; (void)out_size;
    constexpr int T  = 1024;
    constexpr int NC = 16;    // chunks (CH=64)
    constexpr int W  = 288;   // warm-up steps: expected gap ~0.77 ~= TOL
    const float* inputs = (const float*)d_in[0];
    const float* INSC   = (const float*)d_in[1];
    const float* COEFF  = (const float*)d_in[2];
    const float* SQ     = (const float*)d_in[3];
    const float* SMSC   = (const float*)d_in[4];
    const float* SUB    = (const float*)d_in[5];
    const float* CRAK   = (const float*)d_in[6];
    const float* RecK   = (const float*)d_in[7];
    float* out = (float*)d_out;

    int B = in_sizes[0] / (2 * T);            // 4096 for the reference shape
    size_t need = (size_t)B * NC * sizeof(float4);

    if (ws_size < need || (B % 64) != 0) {
        int blocks = (B + 63) / 64;
        hir_scan_kernel<T><<<dim3(blocks), dim3(64), 0, stream>>>(
            inputs, INSC, COEFF, SQ, SMSC, SUB, CRAK, RecK, out, B);
        return;
    }

    float4* st = (float4*)d_ws;
    long total = (long)B * NC;                // 65536 threads = 1024 waves
    int blocks1 = (int)((total + 63) / 64);
    hir_pass1<T, NC, W><<<dim3(blocks1), dim3(64), 0, stream>>>(
        inputs, INSC, COEFF, SQ, SMSC, SUB, CRAK, RecK, out, st, B);
    int blocks2 = (B + 63) / 64;
    hir_pass2<T, NC><<<dim3(blocks2), dim3(64), 0, stream>>>(
        inputs, INSC, COEFF, SQ, SMSC, SUB, CRAK, RecK, out, st, B);
}

// Round 12
// 151.653 us; speedup vs baseline: 1.1840x; 1.1840x over previous
//
#include <hip/hip_runtime.h>
#include <hip/hip_bf16.h>
#include <math.h>

// HIR rainfall-runoff scan — bracketed time-chunking + exact fixup (R12).
// Math/config identical to R8 (validated: pass1 52us, absmax 0.125).
// Structural change only: thread-per-row global accesses (64 lanes x 8KB
// stride = 64 cache lines PER LOAD INSTRUCTION, saturating the CU's LSU/TA
// address pipe — the ~55% stall R8-R11 could not schedule away) are replaced
// by LDS staging: cooperative coalesced row-major loads (512B contiguous per
// inst), compute reads from LDS (pitch 130 => 2-way conflicts only, free),
// main-tile Q written into consumed LDS slots, coalesced write-out.
//
// T=1024 -> NC=16 chunks of CH=64. Warm-up W=320 steps, bracket lo=0 /
// hi=SMSC (monotone map => invariant), merge if gap <= 0.75 (midpoint),
// unmerged chunks recomputed EXACTLY by pass2 from predecessor end state.
// Q[b,t] (t>=1) = fluxes from carry entering step t; Q[b,0] uses the FINAL
// carry (jnp.roll wraparound) with t=0 inputs (chunk NC-1 / pass2 owns it).

struct P {
    float INSC, COEFF, SMSC, RecK, k1, k2, k3, c2;
};

__device__ __forceinline__ P make_params(const float* pINSC, const float* pCOEFF,
                                         const float* pSQ,   const float* pSMSC,
                                         const float* pSUB,  const float* pCRAK,
                                         const float* pRecK) {
    P p;
    p.INSC  = fminf(fmaxf(pINSC[0]  * 5.0f,   0.5f),   5.0f);
    p.COEFF = fminf(fmaxf(pCOEFF[0] * 400.0f, 50.0f),  400.0f);
    float SQ = fminf(fmaxf(pSQ[0]   * 6.0f,   0.0f),   6.0f);
    p.SMSC  = fminf(fmaxf(pSMSC[0]  * 500.0f, 50.0f),  500.0f);
    float SUB  = fminf(fmaxf(pSUB[0],  0.0f), 1.0f);
    float CRAK = fminf(fmaxf(pCRAK[0], 0.0f), 1.0f);
    p.RecK  = fminf(fmaxf(pRecK[0]  * 0.3f,   0.003f), 0.3f);
    float inv = 1.0f / p.SMSC;
    p.k1 = SUB * inv;
    p.k2 = CRAK * inv;
    p.k3 = 10.0f * inv;
    p.c2 = (-SQ * inv) * 1.44269504088896340736f;
    return p;
}

// Full step with Q (identical to validated R8 version).
__device__ __forceinline__ float step(float Prec, float PET, float& sms, float& gw, const P& p) {
    float INT   = fminf(fminf(p.INSC, PET), Prec);
    float INR   = Prec - INT;
    float POT   = PET - INT;
    float S     = fmaxf(fminf(sms, p.SMSC), 0.0f);
    float cap   = p.COEFF * exp2f(p.c2 * S);
    float RMO   = fminf(INR, cap);
    float IRUN  = INR - RMO;
    float SRUN  = (p.k1 * S) * RMO;
    float t2    = RMO - SRUN;
    float REC   = (p.k2 * S) * t2;
    float SMF   = t2 - REC;
    float ETS   = fminf(POT, p.k3 * S);
    float s2    = S + (SMF - ETS);
    float RECnew = REC + fmaxf(s2 - p.SMSC, 0.0f);
    float BAS   = p.RecK * gw;
    float Q     = (SRUN + IRUN) + BAS;
    sms = s2;
    gw  = gw + (RECnew - BAS);
    return Q;
}

// Warm-up step, full state, no Q (exact chain) — R8 version.
__device__ __forceinline__ void stepw(float Prec, float PET, float& sms, float& gw, const P& p) {
    float INT   = fminf(fminf(p.INSC, PET), Prec);
    float INR   = Prec - INT;
    float POT   = PET - INT;
    float S     = fmaxf(fminf(sms, p.SMSC), 0.0f);
    float cap   = p.COEFF * exp2f(p.c2 * S);
    float RMO   = fminf(INR, cap);
    float SRUN  = (p.k1 * S) * RMO;
    float t2    = RMO - SRUN;
    float REC   = (p.k2 * S) * t2;
    float SMF   = t2 - REC;
    float ETS   = fminf(POT, p.k3 * S);
    float s2    = S + (SMF - ETS);
    float RECnew = REC + fmaxf(s2 - p.SMSC, 0.0f);
    float BAS   = p.RecK * gw;
    sms = s2;
    gw  = gw + (RECnew - BAS);
}

// Dual-bracket warm-up step: hi chain carries gw; lo chain is sms-only — R8.
__device__ __forceinline__ void dstep(float Prec, float PET,
                                      float& slo, float& shi, float& gw, const P& p) {
    float INT = fminf(fminf(p.INSC, PET), Prec);
    float INR = Prec - INT;
    float POT = PET - INT;
    {   // hi + gw
        float S     = fmaxf(fminf(shi, p.SMSC), 0.0f);
        float cap   = p.COEFF * exp2f(p.c2 * S);
        float RMO   = fminf(INR, cap);
        float SRUN  = (p.k1 * S) * RMO;
        float t2    = RMO - SRUN;
        float REC   = (p.k2 * S) * t2;
        float SMF   = t2 - REC;
        float ETS   = fminf(POT, p.k3 * S);
        float s2    = S + (SMF - ETS);
        float RECnew = REC + fmaxf(s2 - p.SMSC, 0.0f);
        float BAS   = p.RecK * gw;
        gw  = gw + (RECnew - BAS);
        shi = s2;
    }
    {   // lo, sms only
        float S     = fmaxf(fminf(slo, p.SMSC), 0.0f);
        float cap   = p.COEFF * exp2f(p.c2 * S);
        float RMO   = fminf(INR, cap);
        float SRUN  = (p.k1 * S) * RMO;
        float t2    = RMO - SRUN;
        float REC   = (p.k2 * S) * t2;
        float SMF   = t2 - REC;
        float ETS   = fminf(POT, p.k3 * S);
        slo = S + (SMF - ETS);
    }
}

#define MERGE_TOL 0.75f

template<int T, int NC, int W>
__global__ __launch_bounds__(64, 1)
void hir_pass1(const float* __restrict__ inputs,
               const float* __restrict__ pINSC,  const float* __restrict__ pCOEFF,
               const float* __restrict__ pSQ,    const float* __restrict__ pSMSC,
               const float* __restrict__ pSUB,   const float* __restrict__ pCRAK,
               const float* __restrict__ pRecK,
               float* __restrict__ out, float4* __restrict__ st, int B)
{
    const int lane = threadIdx.x;          // this lane's row within the group
    const int nrg  = B >> 6;               // row groups of 64
    const int rg   = blockIdx.x % nrg;
    const int c    = blockIdx.x / nrg;     // chunk id (block-uniform)
    const int b    = (rg << 6) | lane;

    P p = make_params(pINSC, pCOEFF, pSQ, pSMSC, pSUB, pCRAK, pRecK);

    // LDS tile: 64 rows x 64 steps (128 floats) + pad to pitch 130
    // (pitch 130 => compute read bank = (2*lane+2t)%32 ... 2-way only; 8B aligned rows)
    __shared__ float tile[64][130];

    const size_t rowstride = 2 * (size_t)T;
    float* __restrict__ orow = out + (size_t)b * T;

    constexpr int CH = T / NC;             // 64 steps per chunk
    const int s = c * CH;                  // chunk start timestep
    int t0 = s - W;
    const bool exact = (t0 <= 0);
    if (t0 < 0) t0 = 0;
    const int ntiles = (s + CH - t0) >> 6; // 64-step tiles (all multiples of 64)

    float slo = 0.0f, shi = exact ? 0.0f : p.SMSC, gw = 0.0f, sms = 0.0f;
    bool merged = true;

    const float* __restrict__ gbase = inputs + (size_t)(rg << 6) * rowstride;

    for (int k = 0; k < ntiles; ++k) {
        const int tb = t0 + (k << 6);      // tile base timestep
        __syncthreads();                   // WAR: previous tile fully consumed
        // ---- cooperative coalesced load: row r <- 128 floats @ 2*tb ----
        {
            const float* gt = gbase + 2 * (size_t)tb;
            #pragma unroll 8
            for (int r = 0; r < 64; ++r) {
                const float2* srcr = (const float2*)(gt + (size_t)r * rowstride);
                float2 v = srcr[lane];     // 64 lanes x 8B = 512B contiguous
                *(float2*)&tile[r][2 * lane] = v;
            }
        }
        __syncthreads();                   // RAW: tile visible to all lanes

        if (k < ntiles - 1) {
            // ---- warm-up consume: 64 steps from own row ----
            if (exact) {
                for (int t = 0; t < 64; ++t) {
                    float2 pe = *(const float2*)&tile[lane][2 * t];
                    stepw(pe.x, pe.y, shi, gw, p);
                }
            } else {
                for (int t = 0; t < 64; ++t) {
                    float2 pe = *(const float2*)&tile[lane][2 * t];
                    dstep(pe.x, pe.y, slo, shi, gw, p);
                }
            }
        } else {
            // ---- finalize merge, then main chunk consume ----
            if (exact) slo = shi;
            merged = exact || ((shi - slo) <= MERGE_TOL);
            sms = exact ? shi : (0.5f * (slo + shi));
            for (int t = 0; t < 64; ++t) {
                float2 pe = *(const float2*)&tile[lane][2 * t];
                float q = step(pe.x, pe.y, sms, gw, p);
                tile[lane][t] = q;         // overwrite already-consumed input
            }
            __syncthreads();               // Q tile complete
            // ---- cooperative coalesced write-out: row r, cols s..s+63 ----
            {
                float* gdst = out + (size_t)(rg << 6) * T + s;
                #pragma unroll 8
                for (int r = 0; r < 64; ++r) {
                    float q = tile[r][lane];
                    if (c != 0 || lane != 0)   // t=0 owned by the c=NC-1 path
                        gdst[(size_t)r * T + lane] = q;
                }
            }
        }
    }

    // End state + merged flag for pass 2.
    st[(size_t)c * B + b] = make_float4(sms, gw, merged ? 1.0f : 0.0f, 0.0f);

    // t=0 output: rolled state = FINAL carry (end of last chunk) + t=0 inputs.
    if (c == NC - 1) {
        float2 f0 = *(const float2*)(inputs + (size_t)b * rowstride);
        float ss = sms, gg = gw;
        orow[0] = step(f0.x, f0.y, ss, gg, p);
    }
}

template<int T, int NC>
__global__ __launch_bounds__(64, 1)
void hir_pass2(const float* __restrict__ inputs,
               const float* __restrict__ pINSC,  const float* __restrict__ pCOEFF,
               const float* __restrict__ pSQ,    const float* __restrict__ pSMSC,
               const float* __restrict__ pSUB,   const float* __restrict__ pCRAK,
               const float* __restrict__ pRecK,
               float* __restrict__ out, const float4* __restrict__ st, int B)
{
    int b = blockIdx.x * blockDim.x + threadIdx.x;
    if (b >= B) return;

    P p = make_params(pINSC, pCOEFF, pSQ, pSMSC, pSUB, pCRAK, pRecK);
    constexpr int CH = T / NC;

    const float4* __restrict__ rp = (const float4*)(inputs + (size_t)b * (2 * T));
    float* __restrict__ orow = out + (size_t)b * T;

    float4 s0 = st[b];                 // chunk 0: always exact
    float ex_s = s0.x, ex_g = s0.y;

    for (int c = 1; c < NC; ++c) {
        float4 sc = st[(size_t)c * B + b];
        if (sc.z != 0.0f) {
            ex_s = sc.x; ex_g = sc.y;
            continue;
        }
        float sms = ex_s, gw = ex_g;
        const int i1 = c * (CH >> 1);
        const int i2 = (c + 1) * (CH >> 1);
        float4 cur = rp[i1];
        for (int i = i1; i < i2; ++i) {
            int ni = (i + 1 < i2) ? (i + 1) : i;
            float4 nxt = rp[ni];
            float qa = step(cur.x, cur.y, sms, gw, p);
            float qb = step(cur.z, cur.w, sms, gw, p);
            ((float2*)orow)[i] = make_float2(qa, qb);
            cur = nxt;
        }
        ex_s = sms; ex_g = gw;
        if (c == NC - 1) {
            float4 f0 = rp[0];
            float ss = sms, gg = gw;
            orow[0] = step(f0.x, f0.y, ss, gg, p);
        }
    }
}

// Fallback: monolithic sequential (odd shapes / tiny workspace).
template<int T>
__global__ __launch_bounds__(64, 1)
void hir_scan_kernel(const float* __restrict__ inputs,
                     const float* __restrict__ pINSC,  const float* __restrict__ pCOEFF,
                     const float* __restrict__ pSQ,    const float* __restrict__ pSMSC,
                     const float* __restrict__ pSUB,   const float* __restrict__ pCRAK,
                     const float* __restrict__ pRecK,
                     float* __restrict__ out, int B)
{
    int b = blockIdx.x * blockDim.x + threadIdx.x;
    if (b >= B) return;
    P p = make_params(pINSC, pCOEFF, pSQ, pSMSC, pSUB, pCRAK, pRecK);
    const float4* __restrict__ rp = (const float4*)(inputs + (size_t)b * (2 * T));
    float* __restrict__ orow = out + (size_t)b * T;
    float sms = 0.0f, gw = 0.0f;
    float4 cur = rp[0];
    const float P0 = cur.x, E0 = cur.y;
    constexpr int NI = T / 2;
    for (int i = 0; i < NI; ++i) {
        int ni = (i + 1 < NI) ? (i + 1) : i;
        float4 nxt = rp[ni];
        float qa = step(cur.x, cur.y, sms, gw, p);
        float qb = step(cur.z, cur.w, sms, gw, p);
        if (i == 0) { orow[1] = qb; }
        else        { ((float2*)orow)[i] = make_float2(qa, qb); }
        cur = nxt;
    }
    float ss = sms, gg = gw;
    orow[0] = step(P0, E0, ss, gg, p);
}

extern "C" void kernel_launch(void* const* d_in, const int* in_sizes, int n_in,
                              void* d_out, int out_size, void* d_ws, size_t ws_size,
                              hipStream_t stream) {
    (void)n_in; (void)out_size;
    constexpr int T  = 1024;
    constexpr int NC = 16;    // chunks (CH=64)
    constexpr int W  = 320;   // warm-up steps (validated: absmax 0.125)
    const float* inputs = (const float*)d_in[0];
    const float* INSC   = (const float*)d_in[1];
    const float* COEFF  = (const float*)d_in[2];
    const float* SQ     = (const float*)d_in[3];
    const float* SMSC   = (const float*)d_in[4];
    const float* SUB    = (const float*)d_in[5];
    const float* CRAK   = (const float*)d_in[6];
    const float* RecK   = (const float*)d_in[7];
    float* out = (float*)d_out;

    int B = in_sizes[0] / (2 * T);            // 4096 for the reference shape
    size_t need = (size_t)B * NC * sizeof(float4);

    if (ws_size < need || (B % 64) != 0) {
        int blocks = (B + 63) / 64;
        hir_scan_kernel<T><<<dim3(blocks), dim3(64), 0, stream>>>(
            inputs, INSC, COEFF, SQ, SMSC, SUB, CRAK, RecK, out, B);
        return;
    }

    float4* st = (float4*)d_ws;
    int nrg = B >> 6;                         // 64 row-groups
    int blocks1 = nrg * NC;                   // 1024 blocks x 64 thr = 1024 waves
    hir_pass1<T, NC, W><<<dim3(blocks1), dim3(64), 0, stream>>>(
        inputs, INSC, COEFF, SQ, SMSC, SUB, CRAK, RecK, out, st, B);
    int blocks2 = (B + 63) / 64;
    hir_pass2<T, NC><<<dim3(blocks2), dim3(64), 0, stream>>>(
        inputs, INSC, COEFF, SQ, SMSC, SUB, CRAK, RecK, out, st, B);
}

// Round 13
// 140.384 us; speedup vs baseline: 1.2790x; 1.0803x over previous
//
#include <hip/hip_runtime.h>
#include <hip/hip_bf16.h>
#include <math.h>

// HIR rainfall-runoff scan — bracketed time-chunking + exact fixup (R13).
// Structure/config IDENTICAL to R8 (best validated: pass1 52us, absmax
// 0.125). Single change: exp2f (v_exp_f32, transcendental) replaced by a
// pure-VALU polynomial exp2 — the exp sits on the LOOP-CARRIED dependence
// chain (S -> cap -> RMO -> ... -> s2 -> S), and cross-round evidence
// (R3 295cyc/step single chain; R8 325 dual; R9/R10/R12 restructurings all
// neutral-or-worse) says the wall is that serial chain, dominated by the
// trans op's effective dependent latency. Poly chain ~32 cyc of FMAs.
//
// fast_exp2(y), y in [-4.33, 0]: k=rint(y), f=y-k in [-0.5,0.5],
// 2^f = deg-6 Taylor (rel err ~6e-8, Estrin), scale by exact 2^k via
// __int_as_float((k+127)<<23) multiply. No special cases needed (domain
// bounded); ~1-2 ulp vs v_exp_f32 -> trajectory perturbation damped by the
// contraction, absmax unchanged at tolerance scale.
//
// T=1024 -> NC=16 chunks of CH=64. Warm-up W=320 steps, bracket lo=0 /
// hi=SMSC (monotone map => invariant), merge if gap <= 0.75 (midpoint),
// unmerged chunks recomputed EXACTLY by pass2 from predecessor end state.
// Q[b,t] (t>=1) = fluxes from carry entering step t; Q[b,0] uses the FINAL
// carry (jnp.roll wraparound) with t=0 inputs (chunk NC-1 / pass2 owns it).

struct P {
    float INSC, COEFF, SMSC, RecK, k1, k2, k3, c2;
};

__device__ __forceinline__ float fast_exp2(float y) {
    float k  = rintf(y);                   // v_rndne_f32
    float f  = y - k;                      // |f| <= 0.5
    const float C1 = 0.693147180559945f;
    const float C2 = 0.240226506959101f;
    const float C3 = 0.0555041086648216f;
    const float C4 = 0.00961812910762848f;
    const float C5 = 0.00133335581464284f;
    const float C6 = 1.54035303933816e-4f;
    float f2 = f * f;
    float f4 = f2 * f2;
    float A  = fmaf(C1, f, 1.0f);
    float Bq = fmaf(C3, f, C2);
    float Cq = fmaf(C5, f, C4);
    float p  = fmaf(f4, fmaf(f2, C6, Cq), fmaf(f2, Bq, A));
    int  ki  = (int)k;                     // k in [-5, 0] here
    float sc = __int_as_float((ki + 127) << 23);   // exact 2^k
    return p * sc;
}

__device__ __forceinline__ P make_params(const float* pINSC, const float* pCOEFF,
                                         const float* pSQ,   const float* pSMSC,
                                         const float* pSUB,  const float* pCRAK,
                                         const float* pRecK) {
    P p;
    p.INSC  = fminf(fmaxf(pINSC[0]  * 5.0f,   0.5f),   5.0f);
    p.COEFF = fminf(fmaxf(pCOEFF[0] * 400.0f, 50.0f),  400.0f);
    float SQ = fminf(fmaxf(pSQ[0]   * 6.0f,   0.0f),   6.0f);
    p.SMSC  = fminf(fmaxf(pSMSC[0]  * 500.0f, 50.0f),  500.0f);
    float SUB  = fminf(fmaxf(pSUB[0],  0.0f), 1.0f);
    float CRAK = fminf(fmaxf(pCRAK[0], 0.0f), 1.0f);
    p.RecK  = fminf(fmaxf(pRecK[0]  * 0.3f,   0.003f), 0.3f);
    float inv = 1.0f / p.SMSC;
    p.k1 = SUB * inv;
    p.k2 = CRAK * inv;
    p.k3 = 10.0f * inv;
    p.c2 = (-SQ * inv) * 1.44269504088896340736f;
    return p;
}

// Full step with Q.
__device__ __forceinline__ float step(float Prec, float PET, float& sms, float& gw, const P& p) {
    float INT   = fminf(fminf(p.INSC, PET), Prec);
    float INR   = Prec - INT;
    float POT   = PET - INT;
    float S     = fmaxf(fminf(sms, p.SMSC), 0.0f);
    float cap   = p.COEFF * fast_exp2(p.c2 * S);
    float RMO   = fminf(INR, cap);
    float IRUN  = INR - RMO;
    float SRUN  = (p.k1 * S) * RMO;
    float t2    = RMO - SRUN;
    float REC   = (p.k2 * S) * t2;
    float SMF   = t2 - REC;
    float ETS   = fminf(POT, p.k3 * S);
    float s2    = S + (SMF - ETS);
    float RECnew = REC + fmaxf(s2 - p.SMSC, 0.0f);
    float BAS   = p.RecK * gw;
    float Q     = (SRUN + IRUN) + BAS;
    sms = s2;
    gw  = gw + (RECnew - BAS);
    return Q;
}

// Warm-up step, full state, no Q (exact chain).
__device__ __forceinline__ void stepw(float Prec, float PET, float& sms, float& gw, const P& p) {
    float INT   = fminf(fminf(p.INSC, PET), Prec);
    float INR   = Prec - INT;
    float POT   = PET - INT;
    float S     = fmaxf(fminf(sms, p.SMSC), 0.0f);
    float cap   = p.COEFF * fast_exp2(p.c2 * S);
    float RMO   = fminf(INR, cap);
    float SRUN  = (p.k1 * S) * RMO;
    float t2    = RMO - SRUN;
    float REC   = (p.k2 * S) * t2;
    float SMF   = t2 - REC;
    float ETS   = fminf(POT, p.k3 * S);
    float s2    = S + (SMF - ETS);
    float RECnew = REC + fmaxf(s2 - p.SMSC, 0.0f);
    float BAS   = p.RecK * gw;
    sms = s2;
    gw  = gw + (RECnew - BAS);
}

// Dual-bracket warm-up step: hi chain carries gw; lo chain is sms-only.
__device__ __forceinline__ void dstep(float Prec, float PET,
                                      float& slo, float& shi, float& gw, const P& p) {
    float INT = fminf(fminf(p.INSC, PET), Prec);
    float INR = Prec - INT;
    float POT = PET - INT;
    {   // hi + gw
        float S     = fmaxf(fminf(shi, p.SMSC), 0.0f);
        float cap   = p.COEFF * fast_exp2(p.c2 * S);
        float RMO   = fminf(INR, cap);
        float SRUN  = (p.k1 * S) * RMO;
        float t2    = RMO - SRUN;
        float REC   = (p.k2 * S) * t2;
        float SMF   = t2 - REC;
        float ETS   = fminf(POT, p.k3 * S);
        float s2    = S + (SMF - ETS);
        float RECnew = REC + fmaxf(s2 - p.SMSC, 0.0f);
        float BAS   = p.RecK * gw;
        gw  = gw + (RECnew - BAS);
        shi = s2;
    }
    {   // lo, sms only
        float S     = fmaxf(fminf(slo, p.SMSC), 0.0f);
        float cap   = p.COEFF * fast_exp2(p.c2 * S);
        float RMO   = fminf(INR, cap);
        float SRUN  = (p.k1 * S) * RMO;
        float t2    = RMO - SRUN;
        float REC   = (p.k2 * S) * t2;
        float SMF   = t2 - REC;
        float ETS   = fminf(POT, p.k3 * S);
        slo = S + (SMF - ETS);
    }
}

#define MERGE_TOL 0.75f

template<int T, int NC, int W>
__global__ __launch_bounds__(64, 1)
void hir_pass1(const float* __restrict__ inputs,
               const float* __restrict__ pINSC,  const float* __restrict__ pCOEFF,
               const float* __restrict__ pSQ,    const float* __restrict__ pSMSC,
               const float* __restrict__ pSUB,   const float* __restrict__ pCRAK,
               const float* __restrict__ pRecK,
               float* __restrict__ out, float4* __restrict__ st, int B)
{
    int gid = blockIdx.x * blockDim.x + threadIdx.x;
    int b = gid % B;            // consecutive lanes -> consecutive rows
    int c = gid / B;            // wave-uniform (B % 64 == 0)
    if (c >= NC) return;

    P p = make_params(pINSC, pCOEFF, pSQ, pSMSC, pSUB, pCRAK, pRecK);

    const float4* __restrict__ rp = (const float4*)(inputs + (size_t)b * (2 * T));
    float* __restrict__ orow = out + (size_t)b * T;

    constexpr int CH = T / NC;             // 64 steps
    const int i1 = c * (CH >> 1);          // first main float4 index
    int i0 = i1 - (W >> 1);                // warm-up start
    const bool exact = (i0 <= 0);
    if (i0 < 0) i0 = 0;

    float slo = 0.0f, shi = exact ? 0.0f : p.SMSC, gw = 0.0f;

    // ---- Warm-up: batches of 4 float4 (8 steps), depth-2 copy pipeline ----
    const int nwb = (i1 - i0) >> 2;        // warm-up batches, multiple of 4
    if (nwb > 0) {
        float4 A[4], Bq[4], C[4];
        #pragma unroll
        for (int j = 0; j < 4; ++j) A[j] = rp[i0 + j];
        int k1b = (1 < nwb) ? 1 : 0;
        #pragma unroll
        for (int j = 0; j < 4; ++j) Bq[j] = rp[i0 + 4 * k1b + j];
        if (exact) {
            for (int k = 0; k < nwb; ++k) {
                int kn = (k + 2 < nwb) ? (k + 2) : (nwb - 1);
                #pragma unroll
                for (int j = 0; j < 4; ++j) C[j] = rp[i0 + 4 * kn + j];
                #pragma unroll
                for (int j = 0; j < 4; ++j) {
                    stepw(A[j].x, A[j].y, shi, gw, p);
                    stepw(A[j].z, A[j].w, shi, gw, p);
                }
                #pragma unroll
                for (int j = 0; j < 4; ++j) { A[j] = Bq[j]; Bq[j] = C[j]; }
            }
            slo = shi;
        } else {
            for (int k = 0; k < nwb; ++k) {
                int kn = (k + 2 < nwb) ? (k + 2) : (nwb - 1);
                #pragma unroll
                for (int j = 0; j < 4; ++j) C[j] = rp[i0 + 4 * kn + j];
                #pragma unroll
                for (int j = 0; j < 4; ++j) {
                    dstep(A[j].x, A[j].y, slo, shi, gw, p);
                    dstep(A[j].z, A[j].w, slo, shi, gw, p);
                }
                #pragma unroll
                for (int j = 0; j < 4; ++j) { A[j] = Bq[j]; Bq[j] = C[j]; }
            }
        }
    }
    const bool merged = exact || ((shi - slo) <= MERGE_TOL);
    float sms = exact ? shi : (0.5f * (slo + shi));

    // ---- Main chunk: 32 float4s, same pipeline, store Q pairs ----
    {
        constexpr int nmb = (CH / 2) / 4;  // 8 batches
        float4 A[4], Bq[4], C[4];
        #pragma unroll
        for (int j = 0; j < 4; ++j) A[j] = rp[i1 + j];
        #pragma unroll
        for (int j = 0; j < 4; ++j) Bq[j] = rp[i1 + 4 + j];
        for (int k = 0; k < nmb; ++k) {
            int kn = (k + 2 < nmb) ? (k + 2) : (nmb - 1);
            #pragma unroll
            for (int j = 0; j < 4; ++j) C[j] = rp[i1 + 4 * kn + j];
            int ibase = i1 + 4 * k;
            #pragma unroll
            for (int j = 0; j < 4; ++j) {
                float qa = step(A[j].x, A[j].y, sms, gw, p);
                float qb = step(A[j].z, A[j].w, sms, gw, p);
                if (c == 0 && k == 0 && j == 0) {
                    orow[1] = qb;          // t=0 owned by the c=NC-1 path
                } else {
                    ((float2*)orow)[ibase + j] = make_float2(qa, qb);
                }
            }
            #pragma unroll
            for (int j = 0; j < 4; ++j) { A[j] = Bq[j]; Bq[j] = C[j]; }
        }
    }

    st[(size_t)c * B + b] = make_float4(sms, gw, merged ? 1.0f : 0.0f, 0.0f);

    if (c == NC - 1) {
        float4 f0 = rp[0];
        float ss = sms, gg = gw;
        orow[0] = step(f0.x, f0.y, ss, gg, p);
    }
}

template<int T, int NC>
__global__ __launch_bounds__(64, 1)
void hir_pass2(const float* __restrict__ inputs,
               const float* __restrict__ pINSC,  const float* __restrict__ pCOEFF,
               const float* __restrict__ pSQ,    const float* __restrict__ pSMSC,
               const float* __restrict__ pSUB,   const float* __restrict__ pCRAK,
               const float* __restrict__ pRecK,
               float* __restrict__ out, const float4* __restrict__ st, int B)
{
    int b = blockIdx.x * blockDim.x + threadIdx.x;
    if (b >= B) return;

    P p = make_params(pINSC, pCOEFF, pSQ, pSMSC, pSUB, pCRAK, pRecK);
    constexpr int CH = T / NC;

    const float4* __restrict__ rp = (const float4*)(inputs + (size_t)b * (2 * T));
    float* __restrict__ orow = out + (size_t)b * T;

    float4 s0 = st[b];                 // chunk 0: always exact
    float ex_s = s0.x, ex_g = s0.y;

    for (int c = 1; c < NC; ++c) {
        float4 sc = st[(size_t)c * B + b];
        if (sc.z != 0.0f) {
            ex_s = sc.x; ex_g = sc.y;
            continue;
        }
        float sms = ex_s, gw = ex_g;
        const int i1 = c * (CH >> 1);
        const int i2 = (c + 1) * (CH >> 1);
        float4 cur = rp[i1];
        for (int i = i1; i < i2; ++i) {
            int ni = (i + 1 < i2) ? (i + 1) : i;
            float4 nxt = rp[ni];
            float qa = step(cur.x, cur.y, sms, gw, p);
            float qb = step(cur.z, cur.w, sms, gw, p);
            ((float2*)orow)[i] = make_float2(qa, qb);
            cur = nxt;
        }
        ex_s = sms; ex_g = gw;
        if (c == NC - 1) {
            float4 f0 = rp[0];
            float ss = sms, gg = gw;
            orow[0] = step(f0.x, f0.y, ss, gg, p);
        }
    }
}

// Fallback: monolithic sequential (odd shapes / tiny workspace).
template<int T>
__global__ __launch_bounds__(64, 1)
void hir_scan_kernel(const float* __restrict__ inputs,
                     const float* __restrict__ pINSC,  const float* __restrict__ pCOEFF,
                     const float* __restrict__ pSQ,    const float* __restrict__ pSMSC,
                     const float* __restrict__ pSUB,   const float* __restrict__ pCRAK,
                     const float* __restrict__ pRecK,
                     float* __restrict__ out, int B)
{
    int b = blockIdx.x * blockDim.x + threadIdx.x;
    if (b >= B) return;
    P p = make_params(pINSC, pCOEFF, pSQ, pSMSC, pSUB, pCRAK, pRecK);
    const float4* __restrict__ rp = (const float4*)(inputs + (size_t)b * (2 * T));
    float* __restrict__ orow = out + (size_t)b * T;
    float sms = 0.0f, gw = 0.0f;
    float4 cur = rp[0];
    const float P0 = cur.x, E0 = cur.y;
    constexpr int NI = T / 2;
    for (int i = 0; i < NI; ++i) {
        int ni = (i + 1 < NI) ? (i + 1) : i;
        float4 nxt = rp[ni];
        float qa = step(cur.x, cur.y, sms, gw, p);
        float qb = step(cur.z, cur.w, sms, gw, p);
        if (i == 0) { orow[1] = qb; }
        else        { ((float2*)orow)[i] = make_float2(qa, qb); }
        cur = nxt;
    }
    float ss = sms, gg = gw;
    orow[0] = step(P0, E0, ss, gg, p);
}

extern "C" void kernel_launch(void* const* d_in, const int* in_sizes, int n_in,
                              void* d_out, int out_size, void* d_ws, size_t ws_size,
                              hipStream_t stream) {
    (void)n_in; (void)out_size;
    constexpr int T  = 1024;
    constexpr int NC = 16;    // chunks (CH=64)
    constexpr int W  = 320;   // warm-up steps (validated: absmax 0.125)
    const float* inputs = (const float*)d_in[0];
    const float* INSC   = (const float*)d_in[1];
    const float* COEFF  = (const float*)d_in[2];
    const float* SQ     = (const float*)d_in[3];
    const float* SMSC   = (const float*)d_in[4];
    const float* SUB    = (const float*)d_in[5];
    const float* CRAK   = (const float*)d_in[6];
    const float* RecK   = (const float*)d_in[7];
    float* out = (float*)d_out;

    int B = in_sizes[0] / (2 * T);            // 4096 for the reference shape
    size_t need = (size_t)B * NC * sizeof(float4);

    if (ws_size < need || (B % 64) != 0) {
        int blocks = (B + 63) / 64;
        hir_scan_kernel<T><<<dim3(blocks), dim3(64), 0, stream>>>(
            inputs, INSC, COEFF, SQ, SMSC, SUB, CRAK, RecK, out, B);
        return;
    }

    float4* st = (float4*)d_ws;
    long total = (long)B * NC;                // 65536 threads = 1024 waves
    int blocks1 = (int)((total + 63) / 64);
    hir_pass1<T, NC, W><<<dim3(blocks1), dim3(64), 0, stream>>>(
        inputs, INSC, COEFF, SQ, SMSC, SUB, CRAK, RecK, out, st, B);
    int blocks2 = (B + 63) / 64;
    hir_pass2<T, NC><<<dim3(blocks2), dim3(64), 0, stream>>>(
        inputs, INSC, COEFF, SQ, SMSC, SUB, CRAK, RecK, out, st, B);
}